// Round 14
// baseline (108.644 us; speedup 1.0000x reference)
//
#include <hip/hip_runtime.h>
#include <math.h>

#define BB 4096
#define NN 256
#define FIN 15
#define HH 128
#define HH4 32
#define FOUT 6

typedef __attribute__((ext_vector_type(8))) short short8v;   // 8 bf16 in 4 VGPRs
typedef __attribute__((ext_vector_type(4))) float f32x4;
typedef __attribute__((ext_vector_type(2))) float f32x2;

__device__ __forceinline__ float exp_raw(float x) {   // v_exp_f32: 2^x
    float r;
    asm("v_exp_f32 %0, %1" : "=v"(r) : "v"(x));
    return r;
}

// fast silu/sigmoid: v_exp + v_rcp (no IEEE divide sequence)
__device__ __forceinline__ float silu_f(float z) {
    return z * __builtin_amdgcn_rcpf(1.0f + __expf(-z));
}
__device__ __forceinline__ float sigm_f(float z) {
    return __builtin_amdgcn_rcpf(1.0f + __expf(-z));
}

// paired silu: packed arg-scale (one pk_mul), scalar trans, packed add/mul
__device__ __forceinline__ f32x2 silu2(float a, float b) {
    const f32x2 z = {a, b};
    const f32x2 zs = z * (f32x2){-1.44269504088896340736f, -1.44269504088896340736f};
    f32x2 e;
    e.x = exp_raw(zs.x);                          // 2^(-a*log2e) = exp(-a)
    e.y = exp_raw(zs.y);
    const f32x2 den = e + (f32x2){1.0f, 1.0f};   // v_pk_add_f32
    f32x2 r;
    r.x = __builtin_amdgcn_rcpf(den.x);
    r.y = __builtin_amdgcn_rcpf(den.y);
    return z * r;                                 // v_pk_mul_f32
}

__device__ __forceinline__ unsigned short f2bf(float f) {
    unsigned int u = __builtin_bit_cast(unsigned int, f);
    u += 0x7FFFu + ((u >> 16) & 1u);      // round-to-nearest-even
    return (unsigned short)(u >> 16);
}

// pack 2 f32 -> 2 bf16 in one u32 (low = lo, high = hi)
__device__ __forceinline__ unsigned int cvt_pk_bf16(float lo, float hi) {
    unsigned int r;
    asm("v_cvt_pk_bf16_f32 %0, %1, %2" : "=v"(r) : "v"(lo), "v"(hi));
    return r;
}

// ---------------- prep: weights -> bf16 [n][k] + edge-MLP table in ws -------
// ws layout: ushort w1t[128][32] @0 ; ushort w2t[128][128] @4096 (perm-k);
//            float  etab[2052]   @ushort-offset 20480 (byte 40960)
//            etab[i] = sigmoid( silu(d*eW1+eb1)@eW2 + eb2 ),  d = i/128
__global__ void prep_kernel(const float* __restrict__ nW1,
                            const float* __restrict__ nW2,
                            const float* __restrict__ eW1,
                            const float* __restrict__ eb1,
                            const float* __restrict__ eW2,
                            const float* __restrict__ eb2,
                            unsigned short* __restrict__ ws) {
    const int idx = blockIdx.x * 256 + threadIdx.x;
    if (idx < 4096) {
        const int n = idx >> 5, k = idx & 31;
        ws[idx] = (k < FIN) ? f2bf(nW1[k * HH + n]) : (unsigned short)0;
    } else if (idx < 20480) {
        const int j = idx - 4096;
        const int n = j >> 7, kp = j & 127;
        // inverse of colpos: kp = 32*wvc + 2*lr + half  ->  k = 32*wvc + 16*half + lr
        const int k = 32 * (kp >> 5) + 16 * (kp & 1) + ((kp & 31) >> 1);
        ws[idx] = f2bf(nW2[k * HH + n]);
    } else if (idx < 20480 + 2052) {
        const int i = idx - 20480;
        const float d = (float)i * (1.0f / 128.0f);
        float s = eb2[0];
        #pragma unroll
        for (int t = 0; t < HH4; ++t) {
            float z = d * eW1[t] + eb1[t];
            s += silu_f(z) * eW2[t];
        }
        float* etab = (float*)(ws + 20480);
        etab[i] = sigm_f(s);
    }
}

#define MFMA16(A, B, C) __builtin_amdgcn_mfma_f32_16x16x32_bf16((A), (B), (C), 0, 0, 0)

__launch_bounds__(512)
__global__ void stargnn_kernel(
    const float* __restrict__ x_feat,   // (B,N,FIN)
    const float* __restrict__ coords,   // (B,N,3)
    const float* __restrict__ mask,     // (B,N,1)
    const int*   __restrict__ centers,  // (B,)
    const float* __restrict__ nb1, const float* __restrict__ nb2,
    const float* __restrict__ rW1, const float* __restrict__ rb1,
    const float* __restrict__ rW2, const float* __restrict__ rb2,
    const unsigned short* __restrict__ wbf,  // ws: w1t @0, w2t @4096, etab @20480
    float* __restrict__ out)            // (B,FOUT)
{
    const int b   = blockIdx.x;
    const int tid = threadIdx.x;
    const int wv  = tid >> 6;     // wave 0..7
    const int wvc = wv & 3;       // column-pair group: cols 32*wvc .. +31
    const int rh  = wv >> 2;      // row half of the 128-node tile
    const int l   = tid & 63;
    const int lr  = l & 15;
    const int lg  = l >> 4;

    const int col0 = wvc * 32 + lr;        // first owned column
    const int col1 = wvc * 32 + 16 + lr;   // second owned column

    // LDS = 4096 + 32768 + 1024 = 37888 B -> 4 blocks/CU (32 waves/CU cap)
    __shared__ __align__(16) unsigned int xbf[128 * 8];    // [node][8dw] = 16 bf16 (k 0..15)
    __shared__ __align__(16) unsigned int h1dw[128 * 64];  // half-tile h1, perm cols, XOR-swizzled
    __shared__ __align__(16) float wns[NN];                // w_n*mask^2 (+ center delta)

    const int c = centers[b];

    // ---- edge weight via table: wns[n] = etab(d)*m^2 + (n==c)*m ----
    if (tid < NN) {
        const float* cb = coords + (size_t)b * NN * 3;
        const float c0x = cb[c*3+0], c0y = cb[c*3+1], c0z = cb[c*3+2];
        const float dx = cb[tid*3+0] - c0x;
        const float dy = cb[tid*3+1] - c0y;
        const float dz = cb[tid*3+2] - c0z;
        const float d  = sqrtf(dx*dx + dy*dy + dz*dz);
        const float* etab = (const float*)(wbf + 20480);
        float t = d * 128.0f;
        t = fminf(t, 2047.0f);
        const int   i  = (int)t;
        const float fr = t - (float)i;
        const float v0 = etab[i];
        const float v1 = etab[i + 1];
        const float w  = v0 + fr * (v1 - v0);
        const float m  = mask[(size_t)b * NN + tid];
        wns[tid] = w * m * m + ((tid == c) ? m : 0.0f);
    }

    // ---- bias-as-C-init vectors ----
    const float nb1c0 = nb1[col0], nb1c1 = nb1[col1];
    const float nb2c0 = nb2[col0], nb2c1 = nb2[col1];
    const f32x4 b1i0 = {nb1c0, nb1c0, nb1c0, nb1c0};
    const f32x4 b1i1 = {nb1c1, nb1c1, nb1c1, nb1c1};
    const f32x4 b2i0 = {nb2c0, nb2c0, nb2c0, nb2c0};
    const f32x4 b2i1 = {nb2c1, nb2c1, nb2c1, nb2c1};

    // ---- B-fragments (named registers, whole kernel) ----
    const short8v* w1tp = (const short8v*)wbf;            // [128][32]: idx = n*4 + lg
    const short8v* w2tp = (const short8v*)(wbf + 4096);   // [128][128] perm-k: idx = n*16 + kb*4 + lg
    const short8v b1f0 = w1tp[col0 * 4 + lg];
    const short8v b1f1 = w1tp[col1 * 4 + lg];
    const short8v b2f00 = w2tp[col0 * 16 + 0  + lg];
    const short8v b2f01 = w2tp[col0 * 16 + 4  + lg];
    const short8v b2f02 = w2tp[col0 * 16 + 8  + lg];
    const short8v b2f03 = w2tp[col0 * 16 + 12 + lg];
    const short8v b2f10 = w2tp[col1 * 16 + 0  + lg];
    const short8v b2f11 = w2tp[col1 * 16 + 4  + lg];
    const short8v b2f12 = w2tp[col1 * 16 + 8  + lg];
    const short8v b2f13 = w2tp[col1 * 16 + 12 + lg];

    f32x2 maccs = {0.f, 0.f};
    const short8v azero = {0,0,0,0,0,0,0,0};

    // ---- async-stage: preload half 0's x into registers (512 thr -> 128 nodes) ----
    const int snode = tid >> 2;          // 0..127
    const int skq   = tid & 3;           // k-quad 0..3
    const float* xbase = x_feat + ((size_t)b * NN + snode) * FIN + skq * 4;
    float f0, f1, f2, f3;
    {
        const float* xr = xbase;
        f0 = xr[0]; f1 = xr[1]; f2 = xr[2];
        f3 = (skq < 3) ? xr[3] : 0.0f;   // k=15 pad
    }

    // h1 swizzle: row of 64 dwords, 16 groups of 4 dwords; group g stored at g^(row&15)
    const int wgrp = (16 * wvc + lr) >> 2;  // writer's unswizzled group
    const int wsub = lr & 3;                // writer's dword within group

    // ================= two halves of 128 nodes =================
    // [write xbf][A][L1: read xbf, write h1][B][L2: read h1 + epilogue]
    //  A(q) fences xbf writes and (q=1) L2(0) h1 reads vs L1(1) h1 writes
    //  B(q) fences L1 h1 writes and L1 xbf reads vs next-half xbf writes
    for (int q = 0; q < 2; ++q) {
        xbf[snode * 8 + skq * 2 + 0] = cvt_pk_bf16(f0, f1);
        xbf[snode * 8 + skq * 2 + 1] = cvt_pk_bf16(f2, f3);
        __syncthreads();   // (A)

        if (q < 1) {       // issue next half's global loads early
            const float* xr = xbase + 128 * FIN;
            f0 = xr[0]; f1 = xr[1]; f2 = xr[2];
            f3 = (skq < 3) ? xr[3] : 0.0f;
        }

        // ---- layer 1: h1 = silu(x @ nW1 + nb1) -> swizzled h1dw ----
        #pragma unroll 1
        for (int mi = 0; mi < 4; ++mi) {
            const int mt = rh * 4 + mi;        // row tile 0..7
            short8v a = azero;                 // k=16..31 are zero (never stored)
            if (lg < 2)
                a = *(const short8v*)&xbf[(mt * 16 + lr) * 8 + lg * 4];
            f32x4 d0 = MFMA16(a, b1f0, b1i0);
            f32x4 d1 = MFMA16(a, b1f1, b1i1);
            #define H1W(r) { \
                const int row = mt * 16 + lg * 4 + (r); \
                const int gs  = wgrp ^ (lg * 4 + (r)); \
                const f32x2 s = silu2(d0[r], d1[r]); \
                h1dw[row * 64 + gs * 4 + wsub] = cvt_pk_bf16(s.x, s.y); }
            H1W(0) H1W(1) H1W(2) H1W(3)
            #undef H1W
        }
        __syncthreads();   // (B) h1 ready

        // ---- layer 2 MFMA + epilogue (swizzled group reads: g = 4*kb+lg -> g^lr) ----
        #pragma unroll 1
        for (int mi = 0; mi < 4; ++mi) {
            const int mt = rh * 4 + mi;
            const unsigned int* rbase = h1dw + (mt * 16 + lr) * 64;
            const short8v a0 = *(const short8v*)(rbase + (((0  + lg) ^ lr) << 2));
            const short8v a1 = *(const short8v*)(rbase + (((4  + lg) ^ lr) << 2));
            const short8v a2 = *(const short8v*)(rbase + (((8  + lg) ^ lr) << 2));
            const short8v a3 = *(const short8v*)(rbase + (((12 + lg) ^ lr) << 2));
            f32x4 acc0 = b2i0, acc1 = b2i1;
            acc0 = MFMA16(a0, b2f00, acc0);
            acc0 = MFMA16(a1, b2f01, acc0);
            acc0 = MFMA16(a2, b2f02, acc0);
            acc0 = MFMA16(a3, b2f03, acc0);
            acc1 = MFMA16(a0, b2f10, acc1);
            acc1 = MFMA16(a1, b2f11, acc1);
            acc1 = MFMA16(a2, b2f12, acc1);
            acc1 = MFMA16(a3, b2f13, acc1);

            const f32x4 mw4 = *(const f32x4*)&wns[q * 128 + mt * 16 + lg * 4];
            #define EPIR(r) { \
                const f32x2 s = silu2(acc0[r], acc1[r]); \
                const f32x2 mw2 = {mw4[r], mw4[r]}; \
                maccs += mw2 * s; }
            EPIR(0) EPIR(1) EPIR(2) EPIR(3)
            #undef EPIR
        }
        // no trailing barrier: A(q+1) / pre-tail barrier fences the h1 reads
    }

    // ---- tail scratch aliases the dead h1 region ----
    float* msgs  = (float*)h1dw;          // 128 floats
    float* part2 = (float*)h1dw + 128;    // 256 floats (cross-rh partials)
    float* part4 = (float*)h1dw + 384;    // 512 floats (readout split-K)
    float* r1s   = (float*)h1dw + 896;    // 128 floats

    // ---- reduce msg: lanes (lg) via shfl, row-halves (rh) via LDS ----
    float macc0 = maccs.x, macc1 = maccs.y;
    macc0 += __shfl_xor(macc0, 16);
    macc0 += __shfl_xor(macc0, 32);
    macc1 += __shfl_xor(macc1, 16);
    macc1 += __shfl_xor(macc1, 32);
    __syncthreads();   // all L2(1) h1 reads done before aliased tail writes
    if (lg == 0) {
        part2[rh * HH + col0] = macc0;
        part2[rh * HH + col1] = macc1;
    }
    __syncthreads();
    if (tid < HH) msgs[tid] = part2[tid] + part2[HH + tid];
    __syncthreads();

    // ---- readout layer 1 (f32 VALU, split-K over 4 quarter groups) ----
    {
        const int j  = tid & 127;
        const int kq = tid >> 7;
        float acc = 0.f;
        #pragma unroll 8
        for (int k = kq * 32; k < kq * 32 + 32; ++k)
            acc += msgs[k] * rW1[k * HH + j];
        part4[kq * HH + j] = acc;
    }
    __syncthreads();
    if (tid < HH)
        r1s[tid] = silu_f(part4[tid] + part4[HH + tid] + part4[2 * HH + tid]
                          + part4[3 * HH + tid] + rb1[tid]);
    __syncthreads();

    // ---- final layer: 32 threads per output, shfl reduce ----
    if (tid < 32 * FOUT) {
        const int j  = tid >> 5;        // 0..5
        const int kk = tid & 31;        // 0..31
        float acc = 0.f;
        #pragma unroll
        for (int q2 = 0; q2 < 4; ++q2) {
            const int k = kk * 4 + q2;
            acc += r1s[k] * rW2[k * FOUT + j];
        }
        acc += __shfl_xor(acc, 1);
        acc += __shfl_xor(acc, 2);
        acc += __shfl_xor(acc, 4);
        acc += __shfl_xor(acc, 8);
        acc += __shfl_xor(acc, 16);
        if (kk == 0) out[(size_t)b * FOUT + j] = acc + rb2[j];
    }
}

extern "C" void kernel_launch(void* const* d_in, const int* in_sizes, int n_in,
                              void* d_out, int out_size, void* d_ws, size_t ws_size,
                              hipStream_t stream) {
    const float* x_feat = (const float*)d_in[0];
    const float* coords = (const float*)d_in[1];
    const float* mask   = (const float*)d_in[2];
    const int*   ctr    = (const int*)d_in[3];
    const float* nW1 = (const float*)d_in[4];
    const float* nb1 = (const float*)d_in[5];
    const float* nW2 = (const float*)d_in[6];
    const float* nb2 = (const float*)d_in[7];
    const float* eW1 = (const float*)d_in[8];
    const float* eb1 = (const float*)d_in[9];
    const float* eW2 = (const float*)d_in[10];
    const float* eb2 = (const float*)d_in[11];
    const float* rW1 = (const float*)d_in[12];
    const float* rb1 = (const float*)d_in[13];
    const float* rW2 = (const float*)d_in[14];
    const float* rb2 = (const float*)d_in[15];
    float* out = (float*)d_out;
    unsigned short* wbf = (unsigned short*)d_ws;

    prep_kernel<<<dim3(89), dim3(256), 0, stream>>>(nW1, nW2, eW1, eb1, eW2, eb2, wbf);
    stargnn_kernel<<<dim3(BB), dim3(512), 0, stream>>>(
        x_feat, coords, mask, ctr,
        nb1, nb2, rW1, rb1, rW2, rb2, wbf, out);
}

// Round 15
// 98.121 us; speedup vs baseline: 1.1073x; 1.1073x over previous
//
#include <hip/hip_runtime.h>
#include <math.h>

#define BB 4096
#define NN 256
#define FIN 15
#define HH 128
#define HH4 32
#define FOUT 6

typedef __attribute__((ext_vector_type(8))) short short8v;   // 8 bf16 in 4 VGPRs
typedef __attribute__((ext_vector_type(4))) float f32x4;
typedef __attribute__((ext_vector_type(2))) float f32x2;

// fast silu/sigmoid: v_exp + v_rcp (no IEEE divide sequence)
__device__ __forceinline__ float silu_f(float z) {
    return z * __builtin_amdgcn_rcpf(1.0f + __expf(-z));
}
__device__ __forceinline__ float sigm_f(float z) {
    return __builtin_amdgcn_rcpf(1.0f + __expf(-z));
}

// paired silu: scalar trans (exp/rcp have no packed form), packed add/mul
__device__ __forceinline__ f32x2 silu2(float a, float b) {
    const f32x2 z = {a, b};
    f32x2 e;
    e.x = __expf(-a);
    e.y = __expf(-b);
    const f32x2 den = e + (f32x2){1.0f, 1.0f};   // v_pk_add_f32
    f32x2 r;
    r.x = __builtin_amdgcn_rcpf(den.x);
    r.y = __builtin_amdgcn_rcpf(den.y);
    return z * r;                                 // v_pk_mul_f32
}

__device__ __forceinline__ unsigned short f2bf(float f) {
    unsigned int u = __builtin_bit_cast(unsigned int, f);
    u += 0x7FFFu + ((u >> 16) & 1u);      // round-to-nearest-even
    return (unsigned short)(u >> 16);
}

// pack 2 f32 -> 2 bf16 in one u32 (low = lo, high = hi)
__device__ __forceinline__ unsigned int cvt_pk_bf16(float lo, float hi) {
    unsigned int r;
    asm("v_cvt_pk_bf16_f32 %0, %1, %2" : "=v"(r) : "v"(lo), "v"(hi));
    return r;
}

// ---------------- prep: weights -> bf16 [n][k] + edge-MLP table in ws -------
// ws layout: ushort w1t[128][32] @0 ; ushort w2t[128][128] @4096 (perm-k);
//            float  etab[2052]   @ushort-offset 20480 (byte 40960)
//            etab[i] = sigmoid( silu(d*eW1+eb1)@eW2 + eb2 ),  d = i/128
__global__ void prep_kernel(const float* __restrict__ nW1,
                            const float* __restrict__ nW2,
                            const float* __restrict__ eW1,
                            const float* __restrict__ eb1,
                            const float* __restrict__ eW2,
                            const float* __restrict__ eb2,
                            unsigned short* __restrict__ ws) {
    const int idx = blockIdx.x * 256 + threadIdx.x;
    if (idx < 4096) {
        const int n = idx >> 5, k = idx & 31;
        ws[idx] = (k < FIN) ? f2bf(nW1[k * HH + n]) : (unsigned short)0;
    } else if (idx < 20480) {
        const int j = idx - 4096;
        const int n = j >> 7, kp = j & 127;
        // inverse of colpos: kp = 32*wvc + 2*lr + half  ->  k = 32*wvc + 16*half + lr
        const int k = 32 * (kp >> 5) + 16 * (kp & 1) + ((kp & 31) >> 1);
        ws[idx] = f2bf(nW2[k * HH + n]);
    } else if (idx < 20480 + 2052) {
        const int i = idx - 20480;
        const float d = (float)i * (1.0f / 128.0f);
        float s = eb2[0];
        #pragma unroll
        for (int t = 0; t < HH4; ++t) {
            float z = d * eW1[t] + eb1[t];
            s += silu_f(z) * eW2[t];
        }
        float* etab = (float*)(ws + 20480);
        etab[i] = sigm_f(s);
    }
}

#define MFMA16(A, B, C) __builtin_amdgcn_mfma_f32_16x16x32_bf16((A), (B), (C), 0, 0, 0)

__launch_bounds__(256)
__global__ void stargnn_kernel(
    const float* __restrict__ x_feat,   // (B,N,FIN)
    const float* __restrict__ coords,   // (B,N,3)
    const float* __restrict__ mask,     // (B,N,1)
    const int*   __restrict__ centers,  // (B,)
    const float* __restrict__ nb1, const float* __restrict__ nb2,
    const float* __restrict__ rW1, const float* __restrict__ rb1,
    const float* __restrict__ rW2, const float* __restrict__ rb2,
    const unsigned short* __restrict__ wbf,  // ws: w1t @0, w2t @4096, etab @20480
    float* __restrict__ out)            // (B,FOUT)
{
    const int b   = blockIdx.x;
    const int tid = threadIdx.x;
    const int wv  = tid >> 6;     // wave 0..3 = column-pair group (cols 32*wv..+31)
    const int l   = tid & 63;
    const int lr  = l & 15;
    const int lg  = l >> 4;

    const int col0 = wv * 32 + lr;        // first owned column
    const int col1 = wv * 32 + 16 + lr;   // second owned column

    // LDS = 2048 + 17408 + 1024 = 20480 B exactly -> 8 blocks/CU (32 waves/CU)
    __shared__ __align__(16) unsigned int xbf[64 * 8];    // [node][8dw] = 16 bf16 (k 0..15)
    __shared__ __align__(16) unsigned int h1dw[64 * 68];  // quarter h1, permuted cols
    __shared__ __align__(16) float wns[NN];               // w_n*mask^2 (+ center delta)

    const int c = centers[b];

    // ---- edge weight via table: wns[n] = etab(d)*m^2 + (n==c)*m ----
    {
        const float* cb = coords + (size_t)b * NN * 3;
        const float c0x = cb[c*3+0], c0y = cb[c*3+1], c0z = cb[c*3+2];
        const float dx = cb[tid*3+0] - c0x;
        const float dy = cb[tid*3+1] - c0y;
        const float dz = cb[tid*3+2] - c0z;
        const float d  = sqrtf(dx*dx + dy*dy + dz*dz);
        const float* etab = (const float*)(wbf + 20480);
        float t = d * 128.0f;
        t = fminf(t, 2047.0f);
        const int   i  = (int)t;
        const float fr = t - (float)i;
        const float v0 = etab[i];
        const float v1 = etab[i + 1];
        const float w  = v0 + fr * (v1 - v0);
        const float m  = mask[(size_t)b * NN + tid];
        wns[tid] = w * m * m + ((tid == c) ? m : 0.0f);
    }

    // ---- bias-as-C-init vectors ----
    const float nb1c0 = nb1[col0], nb1c1 = nb1[col1];
    const float nb2c0 = nb2[col0], nb2c1 = nb2[col1];
    const f32x4 b1i0 = {nb1c0, nb1c0, nb1c0, nb1c0};
    const f32x4 b1i1 = {nb1c1, nb1c1, nb1c1, nb1c1};
    const f32x4 b2i0 = {nb2c0, nb2c0, nb2c0, nb2c0};
    const f32x4 b2i1 = {nb2c1, nb2c1, nb2c1, nb2c1};

    // ---- B-fragments (named registers, whole kernel) ----
    const short8v* w1tp = (const short8v*)wbf;            // [128][32]: idx = n*4 + lg
    const short8v* w2tp = (const short8v*)(wbf + 4096);   // [128][128] perm-k: idx = n*16 + kb*4 + lg
    const short8v b1f0 = w1tp[col0 * 4 + lg];
    const short8v b1f1 = w1tp[col1 * 4 + lg];
    const short8v b2f00 = w2tp[col0 * 16 + 0  + lg];
    const short8v b2f01 = w2tp[col0 * 16 + 4  + lg];
    const short8v b2f02 = w2tp[col0 * 16 + 8  + lg];
    const short8v b2f03 = w2tp[col0 * 16 + 12 + lg];
    const short8v b2f10 = w2tp[col1 * 16 + 0  + lg];
    const short8v b2f11 = w2tp[col1 * 16 + 4  + lg];
    const short8v b2f12 = w2tp[col1 * 16 + 8  + lg];
    const short8v b2f13 = w2tp[col1 * 16 + 12 + lg];

    f32x2 maccs = {0.f, 0.f};
    const short8v azero = {0,0,0,0,0,0,0,0};

    // ---- async-stage: preload quarter 0's x into registers ----
    const int snode = tid >> 2;          // 0..63
    const int skq   = tid & 3;           // k-quad 0..3
    const float* xbase = x_feat + ((size_t)b * NN + snode) * FIN + skq * 4;
    float f0, f1, f2, f3;
    {
        const float* xr = xbase;
        f0 = xr[0]; f1 = xr[1]; f2 = xr[2];
        f3 = (skq < 3) ? xr[3] : 0.0f;   // k=15 pad
    }

    // ================= four quarters of 64 nodes =================
    // Barrier scheme: [write xbf][A][L1: read xbf, write h1][B][L2: read h1]
    //  - A(q) fences xbf writes AND (q>0) L2(q-1) h1 reads vs L1(q) h1 writes
    //  - B(q) fences L1 h1 writes AND L1 xbf reads vs next-quarter xbf writes
    for (int q = 0; q < 4; ++q) {
        // ---- write staged regs -> xbf ----
        xbf[snode * 8 + skq * 2 + 0] = cvt_pk_bf16(f0, f1);
        xbf[snode * 8 + skq * 2 + 1] = cvt_pk_bf16(f2, f3);
        __syncthreads();   // (A)

        // ---- issue next quarter's global loads early (hide under L1+L2) ----
        if (q < 3) {
            const float* xr = xbase + (q + 1) * 64 * FIN;
            f0 = xr[0]; f1 = xr[1]; f2 = xr[2];
            f3 = (skq < 3) ? xr[3] : 0.0f;
        }

        // ---- layer 1: h1 = silu(x @ nW1 + nb1) -> permuted h1dw ----
        #pragma unroll 1
        for (int mt = 0; mt < 4; ++mt) {
            short8v a = azero;                 // k=16..31 are zero (never stored)
            if (lg < 2)
                a = *(const short8v*)&xbf[(mt * 16 + lr) * 8 + lg * 4];
            f32x4 d0 = MFMA16(a, b1f0, b1i0);
            f32x4 d1 = MFMA16(a, b1f1, b1i1);
            #define H1W(r) { \
                const int row = mt * 16 + lg * 4 + (r); \
                const f32x2 s = silu2(d0[r], d1[r]); \
                h1dw[row * 68 + 16 * wv + lr] = cvt_pk_bf16(s.x, s.y); }
            H1W(0) H1W(1) H1W(2) H1W(3)
            #undef H1W
        }
        __syncthreads();   // (B) h1 ready

        // ---- layer 2 MFMA + epilogue ----
        #pragma unroll 1
        for (int mt = 0; mt < 4; ++mt) {
            const unsigned short* arow = (const unsigned short*)h1dw + (mt * 16 + lr) * 136 + lg * 8;
            const short8v a0 = *(const short8v*)(arow);
            const short8v a1 = *(const short8v*)(arow + 32);
            const short8v a2 = *(const short8v*)(arow + 64);
            const short8v a3 = *(const short8v*)(arow + 96);
            f32x4 acc0 = b2i0, acc1 = b2i1;
            acc0 = MFMA16(a0, b2f00, acc0);
            acc0 = MFMA16(a1, b2f01, acc0);
            acc0 = MFMA16(a2, b2f02, acc0);
            acc0 = MFMA16(a3, b2f03, acc0);
            acc1 = MFMA16(a0, b2f10, acc1);
            acc1 = MFMA16(a1, b2f11, acc1);
            acc1 = MFMA16(a2, b2f12, acc1);
            acc1 = MFMA16(a3, b2f13, acc1);

            const f32x4 mw4 = *(const f32x4*)&wns[q * 64 + mt * 16 + lg * 4];
            #define EPIR(r) { \
                const f32x2 s = silu2(acc0[r], acc1[r]); \
                const f32x2 mw2 = {mw4[r], mw4[r]}; \
                maccs += mw2 * s; }
            EPIR(0) EPIR(1) EPIR(2) EPIR(3)
            #undef EPIR
        }
        // no barrier here: A(q+1) / pre-tail barrier fences the h1 reads
    }

    // ---- tail scratch aliases the dead h1 region ----
    float* msgs  = (float*)h1dw;          // 128 floats
    float* part2 = (float*)h1dw + 128;    // 256 floats
    float* r1s   = (float*)h1dw + 384;    // 128 floats

    // ---- reduce msg across lg groups (shfl) ----
    float macc0 = maccs.x, macc1 = maccs.y;
    macc0 += __shfl_xor(macc0, 16);
    macc0 += __shfl_xor(macc0, 32);
    macc1 += __shfl_xor(macc1, 16);
    macc1 += __shfl_xor(macc1, 32);
    __syncthreads();   // all L2(3) h1 reads done before aliased tail writes
    if (lg == 0) {
        msgs[col0] = macc0;
        msgs[col1] = macc1;
    }
    __syncthreads();

    // ---- readout layer 1 (f32 VALU, split-K over 2 half groups) ----
    {
        const int j  = tid & 127;
        const int kh = tid >> 7;
        float acc = 0.f;
        #pragma unroll 8
        for (int k = kh * 64; k < kh * 64 + 64; ++k)
            acc += msgs[k] * rW1[k * HH + j];
        part2[kh * HH + j] = acc;
    }
    __syncthreads();
    if (tid < HH)
        r1s[tid] = silu_f(part2[tid] + part2[HH + tid] + rb1[tid]);
    __syncthreads();

    // ---- final layer: 32 threads per output, shfl reduce ----
    if (tid < 32 * FOUT) {
        const int j  = tid >> 5;        // 0..5
        const int kk = tid & 31;        // 0..31
        float acc = 0.f;
        #pragma unroll
        for (int q2 = 0; q2 < 4; ++q2) {
            const int k = kk * 4 + q2;
            acc += r1s[k] * rW2[k * FOUT + j];
        }
        acc += __shfl_xor(acc, 1);
        acc += __shfl_xor(acc, 2);
        acc += __shfl_xor(acc, 4);
        acc += __shfl_xor(acc, 8);
        acc += __shfl_xor(acc, 16);
        if (kk == 0) out[(size_t)b * FOUT + j] = acc + rb2[j];
    }
}

extern "C" void kernel_launch(void* const* d_in, const int* in_sizes, int n_in,
                              void* d_out, int out_size, void* d_ws, size_t ws_size,
                              hipStream_t stream) {
    const float* x_feat = (const float*)d_in[0];
    const float* coords = (const float*)d_in[1];
    const float* mask   = (const float*)d_in[2];
    const int*   ctr    = (const int*)d_in[3];
    const float* nW1 = (const float*)d_in[4];
    const float* nb1 = (const float*)d_in[5];
    const float* nW2 = (const float*)d_in[6];
    const float* nb2 = (const float*)d_in[7];
    const float* eW1 = (const float*)d_in[8];
    const float* eb1 = (const float*)d_in[9];
    const float* eW2 = (const float*)d_in[10];
    const float* eb2 = (const float*)d_in[11];
    const float* rW1 = (const float*)d_in[12];
    const float* rb1 = (const float*)d_in[13];
    const float* rW2 = (const float*)d_in[14];
    const float* rb2 = (const float*)d_in[15];
    float* out = (float*)d_out;
    unsigned short* wbf = (unsigned short*)d_ws;

    prep_kernel<<<dim3(89), dim3(256), 0, stream>>>(nW1, nW2, eW1, eb1, eW2, eb2, wbf);
    stargnn_kernel<<<dim3(BB), dim3(256), 0, stream>>>(
        x_feat, coords, mask, ctr,
        nb1, nb2, rW1, rb1, rW2, rb2, wbf, out);
}